// Round 1
// baseline (530.635 us; speedup 1.0000x reference)
//
#include <hip/hip_runtime.h>
#include <hip/hip_bf16.h>

typedef __bf16 v8bf __attribute__((ext_vector_type(8)));
typedef float  v4f  __attribute__((ext_vector_type(4)));

// fast tanh: (e^2x - 1) / (e^2x + 1) via v_exp_f32 + v_rcp_f32.
// clamp to +-15 (tanh saturated there anyway) so exp2 can't overflow to inf.
__device__ __forceinline__ float fast_tanh(float x) {
    x = fminf(fmaxf(x, -15.f), 15.f);
    float t = __builtin_amdgcn_exp2f(x * 2.885390081777927f);  // e^{2x}
    return (t - 1.f) * __builtin_amdgcn_rcpf(t + 1.f);
}

// ---------------------------------------------------------------------------
// k01: fused prep.
//  blocks 0..127  : W2 fp32 -> bf16 swizzle into MFMA B-fragment order
//                   w2f[ctg(32)][kt(16)][lane(64)][j(8)]; n=ctg*16+(lane&15),
//                   k=kt*32+(lane>>4)*8+j.
//  blocks 128..135: eqc[b][d] = (emotion[b,:] @ W1)[d] + b1[d] + b2[d]
//                   + zero-init of the logits accumulator (k2 uses atomicAdd).
//  k0 and k1 are independent -> run concurrently instead of serially.
// ---------------------------------------------------------------------------
__global__ __launch_bounds__(256) void k01_prep(const float* __restrict__ W2,
                                                __bf16* __restrict__ w2f,
                                                const float* __restrict__ emo,
                                                const float* __restrict__ W1,
                                                const float* __restrict__ b1,
                                                const float* __restrict__ b2,
                                                float* __restrict__ eqc,
                                                float* __restrict__ logits) {
    if (blockIdx.x < 128) {
        int tid = blockIdx.x * 256 + threadIdx.x;   // 0..32767
        int ctg  = tid >> 10;                       // 0..31
        int kt   = (tid >> 6) & 15;                 // 0..15
        int lane = tid & 63;
        int quad = lane >> 4, col = lane & 15;
        int n = ctg * 16 + col;
        int kbase = kt * 32 + quad * 8;
        v8bf v;
#pragma unroll
        for (int j = 0; j < 8; ++j) v[j] = (__bf16)W2[(kbase + j) * 512 + n];
        *(v8bf*)&w2f[(size_t)tid * 8] = v;
    } else {
        int b = blockIdx.x - 128, t = threadIdx.x;
        // zero logits: 8 blocks * 256 threads * 32 = 65536
#pragma unroll
        for (int i = 0; i < 32; ++i) logits[(b * 256 + t) * 32 + i] = 0.f;

        __shared__ float emos[512];
        emos[t]       = emo[b * 512 + t];
        emos[t + 256] = emo[b * 512 + t + 256];
        __syncthreads();
#pragma unroll
        for (int rep = 0; rep < 2; ++rep) {
            int d = t + rep * 256;
            float acc = 0.f;
            for (int k = 0; k < 512; ++k) acc += emos[k] * W1[k * 512 + d];
            eqc[b * 512 + d] = acc + b1[d] + b2[d];
        }
    }
}

// ---------------------------------------------------------------------------
// k2: fused  logits[r] = sum_d tanh(eqc[b,d] + (sents@W2)[r,d]) * W3[d]
//     64 rows/block; sents tile fp32->bf16 into 64KB LDS, XOR-16B-chunk
//     swizzle (chunk c of row r at c ^ (r&15)) -> conflict-free ds_read_b128.
//     4 waves: (row_half, col_half) 2x2 split; each wave 32 rows x 256 cols.
//     RESTRUCTURED kt-outer: one A-frag pair load feeds all 8 column strips
//     (32 MFMAs) -> ds_read_b128 per wave 256 -> 32 (8x LDS traffic cut).
//     acc[8][4] = 128 VGPR, all statically indexed; __launch_bounds__(256,2)
//     keeps it within 256 VGPR so LDS-limited occupancy (2 blk/CU) holds.
//     Layouts (learn_hip m89/m120): A: m=lane&15, k=quad*8+j;
//     B: n=lane&15, k=quad*8+j; C/D: col=lane&15, row=quad*4+reg.
// ---------------------------------------------------------------------------
__global__ __launch_bounds__(256, 2) void k2_logits(const float* __restrict__ sents,
                                                    const __bf16* __restrict__ w2f,
                                                    const float* __restrict__ eqc,
                                                    const float* __restrict__ W3,
                                                    float* __restrict__ logits) {
    __shared__ __bf16 As[64 * 512];             // 65536 B
    const int t = threadIdx.x;
    const int row0 = blockIdx.x * 64;           // global row base (b*L + l)
    const int bidx = row0 >> 13;                // row / 8192 = batch index

    // stage A: 64 rows x 512 cols; each thread converts one 8-float chunk/iter
#pragma unroll
    for (int it = 0; it < 16; ++it) {
        int idx = t + it * 256;
        int r = idx >> 6, c = idx & 63;         // c = 8-element chunk id
        const float4* src = (const float4*)&sents[(size_t)(row0 + r) * 512 + (c << 3)];
        float4 f0 = src[0], f1 = src[1];
        v8bf v;
        v[0] = (__bf16)f0.x; v[1] = (__bf16)f0.y; v[2] = (__bf16)f0.z; v[3] = (__bf16)f0.w;
        v[4] = (__bf16)f1.x; v[5] = (__bf16)f1.y; v[6] = (__bf16)f1.z; v[7] = (__bf16)f1.w;
        *(v8bf*)&As[r * 512 + ((c ^ (r & 15)) << 3)] = v;
    }
    __syncthreads();

    const int wave = t >> 6, lane = t & 63;
    const int quad = lane >> 4, lcol = lane & 15;
    const int row_half = wave >> 1, col_half = wave & 1;
    const int rbase_local = row_half * 32;      // this wave's first row

    v4f acc[8][4];                              // [ct][{00,01,10,11}]
#pragma unroll
    for (int ct = 0; ct < 8; ++ct)
#pragma unroll
        for (int q = 0; q < 4; ++q) acc[ct][q] = (v4f){0.f, 0.f, 0.f, 0.f};

    const __bf16* arow = &As[(rbase_local + lcol) * 512];

    for (int kt = 0; kt < 16; ++kt) {
        const int sc = ((kt * 4 + quad) ^ lcol) << 3;   // swizzled chunk offset
        v8bf a0 = *(const v8bf*)(arow + sc);
        v8bf a1 = *(const v8bf*)(arow + 16 * 512 + sc);
#pragma unroll
        for (int ct = 0; ct < 8; ++ct) {
            const int ctg = (col_half * 8 + ct) * 2;
            const __bf16* bp = &w2f[(size_t)((ctg * 16 + kt) * 64 + lane) * 8];
            v8bf b0 = *(const v8bf*)bp;
            v8bf b1 = *(const v8bf*)(bp + 16 * 64 * 8); // ctg+1 slab (cols +16)
            acc[ct][0] = __builtin_amdgcn_mfma_f32_16x16x32_bf16(a0, b0, acc[ct][0], 0, 0, 0);
            acc[ct][1] = __builtin_amdgcn_mfma_f32_16x16x32_bf16(a0, b1, acc[ct][1], 0, 0, 0);
            acc[ct][2] = __builtin_amdgcn_mfma_f32_16x16x32_bf16(a1, b0, acc[ct][2], 0, 0, 0);
            acc[ct][3] = __builtin_amdgcn_mfma_f32_16x16x32_bf16(a1, b1, acc[ct][3], 0, 0, 0);
        }
    }

    // epilogue: tanh(eqc + v) * W3, accumulate per-row partials in regs
    float rowacc[8] = {0.f, 0.f, 0.f, 0.f, 0.f, 0.f, 0.f, 0.f};
#pragma unroll
    for (int ct = 0; ct < 8; ++ct) {
        const int c0 = (col_half * 8 + ct) * 32;
        float e0  = eqc[bidx * 512 + c0 + lcol];
        float e1  = eqc[bidx * 512 + c0 + 16 + lcol];
        float w30 = W3[c0 + lcol];
        float w31 = W3[c0 + 16 + lcol];
#pragma unroll
        for (int i = 0; i < 4; ++i) {
            rowacc[i]     += fast_tanh(e0 + acc[ct][0][i]) * w30
                           + fast_tanh(e1 + acc[ct][1][i]) * w31;
            rowacc[4 + i] += fast_tanh(e0 + acc[ct][2][i]) * w30
                           + fast_tanh(e1 + acc[ct][3][i]) * w31;
        }
    }
    // reduce over the 16 lanes of each quad (cols)
#pragma unroll
    for (int off = 1; off < 16; off <<= 1)
#pragma unroll
        for (int i = 0; i < 8; ++i) rowacc[i] += __shfl_xor(rowacc[i], off, 16);

    if (lcol == 0) {
        int rbase = row0 + rbase_local + quad * 4;
#pragma unroll
        for (int i = 0; i < 4; ++i) {
            atomicAdd(&logits[rbase + i], rowacc[i]);
            atomicAdd(&logits[rbase + 16 + i], rowacc[4 + i]);
        }
    }
}

// ---------------------------------------------------------------------------
// k3: per-batch softmax over L=8192 + inclusive cumsum -> sw (s), cw (c).
//     1024 threads/block (8 elems/thread): shorter scan depth, 4x the load
//     parallelism on the 8 active CUs.
// ---------------------------------------------------------------------------
__global__ __launch_bounds__(1024) void k3_softmax(const float* __restrict__ logits,
                                                   float* __restrict__ sw,
                                                   float* __restrict__ cw) {
    int b = blockIdx.x, t = threadIdx.x;
    const float* lg = logits + b * 8192;
    float v[8];
    float m = -1e30f;
#pragma unroll
    for (int i = 0; i < 8; ++i) { v[i] = lg[t * 8 + i]; m = fmaxf(m, v[i]); }
    __shared__ float red[1024];
    red[t] = m; __syncthreads();
    for (int s = 512; s > 0; s >>= 1) {
        if (t < s) red[t] = fmaxf(red[t], red[t + s]);
        __syncthreads();
    }
    float M = red[0]; __syncthreads();
    float sum = 0.f;
#pragma unroll
    for (int i = 0; i < 8; ++i) {
        v[i] = __builtin_amdgcn_exp2f((v[i] - M) * 1.4426950408889634f);
        sum += v[i];
    }
    red[t] = sum; __syncthreads();
    // Hillis-Steele inclusive scan over per-thread sums
    for (int off = 1; off < 1024; off <<= 1) {
        float add = (t >= off) ? red[t - off] : 0.f;
        __syncthreads();
        red[t] += add;
        __syncthreads();
    }
    float total = red[1023];
    float excl = red[t] - sum;              // exclusive prefix of thread sums
    float inv = 1.f / total;
    float run = excl;
#pragma unroll
    for (int i = 0; i < 8; ++i) {
        run += v[i];
        sw[b * 8192 + t * 8 + i] = v[i] * inv;
        cw[b * 8192 + t * 8 + i] = run * inv;
    }
}

// ---------------------------------------------------------------------------
// k4: out = (c-s)*pre + s*self + (1-c)*pos   (fp32 streaming, float4/thread,
//     grid-stride @2048 blocks). sents loaded normally (L3-warm from k2);
//     pre/pos/out use non-temporal hints to avoid evicting it.
// ---------------------------------------------------------------------------
__global__ __launch_bounds__(256) void k4_combine(const float* __restrict__ sents,
                                                  const float* __restrict__ pre,
                                                  const float* __restrict__ pos,
                                                  const float* __restrict__ sw,
                                                  const float* __restrict__ cw,
                                                  float* __restrict__ out) {
    const size_t stride = (size_t)gridDim.x * 256;
    for (size_t g = (size_t)blockIdx.x * 256 + threadIdx.x; g < 8388608ull; g += stride) {
        size_t base = g << 2;                           // 4 floats per thread
        int row = (int)(g >> 7);                        // 128 threads per row
        float s = sw[row], c = cw[row];
        float pw = c - s, qw = 1.0f - c;
        v4f a = *(const v4f*)&sents[base];
        v4f p = __builtin_nontemporal_load((const v4f*)&pre[base]);
        v4f q = __builtin_nontemporal_load((const v4f*)&pos[base]);
        v4f o = pw * p + s * a + qw * q;
        __builtin_nontemporal_store(o, (v4f*)&out[base]);
    }
}

// ---------------------------------------------------------------------------
extern "C" void kernel_launch(void* const* d_in, const int* in_sizes, int n_in,
                              void* d_out, int out_size, void* d_ws, size_t ws_size,
                              hipStream_t stream) {
    const float* emo   = (const float*)d_in[0];   // (8,1,512)
    const float* sents = (const float*)d_in[1];   // (8,8192,512)
    const float* pre   = (const float*)d_in[2];
    const float* pos   = (const float*)d_in[3];
    const float* W1    = (const float*)d_in[4];   // (512,512)
    const float* b1    = (const float*)d_in[5];
    const float* W2    = (const float*)d_in[6];   // (512,512)
    const float* b2    = (const float*)d_in[7];
    const float* W3    = (const float*)d_in[8];   // (512,1)
    // b3 = d_in[9]: constant shift -> cancels in softmax (and is zero)
    float* out = (float*)d_out;

    char* ws = (char*)d_ws;
    __bf16* w2f   = (__bf16*)ws;                    // 524288 B
    float* eqc    = (float*)(ws + 524288);          //  16384 B (8x512)
    float* logits = (float*)(ws + 540672);          // 262144 B (8x8192)
    float* sw     = (float*)(ws + 802816);          // 262144 B
    float* cw     = (float*)(ws + 1064960);         // 262144 B  (total ~1.27 MB)

    k01_prep<<<136, 256, 0, stream>>>(W2, w2f, emo, W1, b1, b2, eqc, logits);
    k2_logits<<<1024, 256, 0, stream>>>(sents, w2f, eqc, W3, logits);
    k3_softmax<<<8, 1024, 0, stream>>>(logits, sw, cw);
    k4_combine<<<2048, 256, 0, stream>>>(sents, pre, pos, sw, cw, out);
}

// Round 2
// 477.337 us; speedup vs baseline: 1.1117x; 1.1117x over previous
//
#include <hip/hip_runtime.h>
#include <hip/hip_bf16.h>

typedef __bf16 v8bf __attribute__((ext_vector_type(8)));
typedef float  v4f  __attribute__((ext_vector_type(4)));

// fast tanh: (e^2x - 1) / (e^2x + 1) via v_exp_f32 + v_rcp_f32.
// clamp to +-15 (tanh saturated there anyway) so exp2 can't overflow to inf.
__device__ __forceinline__ float fast_tanh(float x) {
    x = fminf(fmaxf(x, -15.f), 15.f);
    float t = __builtin_amdgcn_exp2f(x * 2.885390081777927f);  // e^{2x}
    return (t - 1.f) * __builtin_amdgcn_rcpf(t + 1.f);
}

__device__ __forceinline__ v8bf cvt8(float4 f0, float4 f1) {
    v8bf v;
    v[0] = (__bf16)f0.x; v[1] = (__bf16)f0.y; v[2] = (__bf16)f0.z; v[3] = (__bf16)f0.w;
    v[4] = (__bf16)f1.x; v[5] = (__bf16)f1.y; v[6] = (__bf16)f1.z; v[7] = (__bf16)f1.w;
    return v;
}

// ---------------------------------------------------------------------------
// k01: fused prep.
//  blocks 0..127  : W2 fp32 -> bf16 swizzle into MFMA B-fragment order
//                   w2f[ctg(32)][kt(16)][lane(64)][j(8)]; n=ctg*16+(lane&15),
//                   k=kt*32+(lane>>4)*8+j.
//  blocks 128..191: eqc[b][d] = (emotion[b,:] @ W1)[d] + b1[d] + b2[d]
//                   8 batches x 8 d-slices of 64; per block 256 threads =
//                   64 d x 4 k-slices (wave-uniform k -> scalar emo loads),
//                   LDS reduce. Spreads the 8 MB W1 stream over 64 CUs
//                   (was 8 -> per-CU BW floor ~40us, now ~5us).
//  No logits zero-init needed anymore (k2 no longer uses atomics).
// ---------------------------------------------------------------------------
__global__ __launch_bounds__(256) void k01_prep(const float* __restrict__ W2,
                                                __bf16* __restrict__ w2f,
                                                const float* __restrict__ emo,
                                                const float* __restrict__ W1,
                                                const float* __restrict__ b1,
                                                const float* __restrict__ b2,
                                                float* __restrict__ eqc) {
    if (blockIdx.x < 128) {
        int tid = blockIdx.x * 256 + threadIdx.x;   // 0..32767
        int ctg  = tid >> 10;                       // 0..31
        int kt   = (tid >> 6) & 15;                 // 0..15
        int lane = tid & 63;
        int quad = lane >> 4, col = lane & 15;
        int n = ctg * 16 + col;
        int kbase = kt * 32 + quad * 8;
        v8bf v;
#pragma unroll
        for (int j = 0; j < 8; ++j) v[j] = (__bf16)W2[(kbase + j) * 512 + n];
        *(v8bf*)&w2f[(size_t)tid * 8] = v;
    } else {
        __shared__ float part[4][64];
        int bb = blockIdx.x - 128;                  // 0..63
        int b = bb >> 3, d0 = (bb & 7) << 6;
        int t = threadIdx.x;
        int dl = t & 63, ks = t >> 6;               // wave-uniform ks
        const float* eb = emo + b * 512;
        float acc = 0.f;
        int kend = ks * 128 + 128;
        for (int k = ks * 128; k < kend; ++k)
            acc += eb[k] * W1[k * 512 + d0 + dl];
        part[ks][dl] = acc;
        __syncthreads();
        if (ks == 0) {
            int d = d0 + dl;
            float r = part[0][dl] + part[1][dl] + part[2][dl] + part[3][dl];
            eqc[b * 512 + d] = r + b1[d] + b2[d];
        }
    }
}

// ---------------------------------------------------------------------------
// k2: fused  logits[r] = sum_d tanh(eqc[b,d] + (sents@W2)[r,d]) * W3[d]
//     NO LDS STAGING: the mfma_16x16x32 A-fragment (lane m=lcol reads 8
//     contiguous k) is a row-contiguous 32B global read from sents; convert
//     fp32->bf16 in-reg. Removes the 64KB LDS tile, the stage barrier, and
//     the vmcnt(0) block-wide drain that serialized the old version
//     (measured: MfmaUtil 10%, VALUBusy 13%, occupancy 22% -- all idle).
//     4 waves: (row_half, col_half) 2x2 split; each wave 32 rows x 256 cols.
//     kt-outer: one A-frag pair feeds all 8 column strips (32 MFMAs).
//     Each row read by 2 co-resident waves -> 2nd read hits L1/L2.
//     B (w2f, 512KB) is L2-resident. acc[8][4]=128 VGPR, static indexing.
//     Col-half partial logits combined via 256B LDS -> plain store,
//     no atomicAdd, no zero-init.
//     Layouts (learn_hip m89/m120): A: m=lane&15, k=quad*8+j;
//     B: n=lane&15, k=quad*8+j; C/D: col=lane&15, row=quad*4+reg.
// ---------------------------------------------------------------------------
__global__ __launch_bounds__(256, 2) void k2_logits(const float* __restrict__ sents,
                                                    const __bf16* __restrict__ w2f,
                                                    const float* __restrict__ eqc,
                                                    const float* __restrict__ W3,
                                                    float* __restrict__ logits) {
    __shared__ float part[64];
    const int t = threadIdx.x;
    const int row0 = blockIdx.x * 64;           // global row base (b*L + l)
    const int bidx = row0 >> 13;                // row / 8192 = batch index

    const int wave = t >> 6, lane = t & 63;
    const int quad = lane >> 4, lcol = lane & 15;
    const int row_half = wave >> 1, col_half = wave & 1;
    const int rbase_local = row_half * 32;      // this wave's first row

    v4f acc[8][4];                              // [ct][{00,01,10,11}]
#pragma unroll
    for (int ct = 0; ct < 8; ++ct)
#pragma unroll
        for (int q = 0; q < 4; ++q) acc[ct][q] = (v4f){0.f, 0.f, 0.f, 0.f};

    // lane's A row pointers: a0 tile rows rbase+lcol, a1 tile +16 rows
    const float* a0p = &sents[(size_t)(row0 + rbase_local + lcol) * 512 + quad * 8];
    const float* a1p = a0p + 16 * 512;

#pragma unroll 2
    for (int kt = 0; kt < 16; ++kt) {
        const float4* p0 = (const float4*)(a0p + kt * 32);
        const float4* p1 = (const float4*)(a1p + kt * 32);
        float4 f00 = p0[0], f01 = p0[1];
        float4 f10 = p1[0], f11 = p1[1];
        v8bf a0 = cvt8(f00, f01);
        v8bf a1 = cvt8(f10, f11);
#pragma unroll
        for (int ct = 0; ct < 8; ++ct) {
            const int ctg = (col_half * 8 + ct) * 2;
            const __bf16* bp = &w2f[(size_t)((ctg * 16 + kt) * 64 + lane) * 8];
            v8bf b0 = *(const v8bf*)bp;
            v8bf b1 = *(const v8bf*)(bp + 16 * 64 * 8); // ctg+1 slab (cols +16)
            acc[ct][0] = __builtin_amdgcn_mfma_f32_16x16x32_bf16(a0, b0, acc[ct][0], 0, 0, 0);
            acc[ct][1] = __builtin_amdgcn_mfma_f32_16x16x32_bf16(a0, b1, acc[ct][1], 0, 0, 0);
            acc[ct][2] = __builtin_amdgcn_mfma_f32_16x16x32_bf16(a1, b0, acc[ct][2], 0, 0, 0);
            acc[ct][3] = __builtin_amdgcn_mfma_f32_16x16x32_bf16(a1, b1, acc[ct][3], 0, 0, 0);
        }
    }

    // epilogue: tanh(eqc + v) * W3, accumulate per-row partials in regs
    float rowacc[8] = {0.f, 0.f, 0.f, 0.f, 0.f, 0.f, 0.f, 0.f};
#pragma unroll
    for (int ct = 0; ct < 8; ++ct) {
        const int c0 = (col_half * 8 + ct) * 32;
        float e0  = eqc[bidx * 512 + c0 + lcol];
        float e1  = eqc[bidx * 512 + c0 + 16 + lcol];
        float w30 = W3[c0 + lcol];
        float w31 = W3[c0 + 16 + lcol];
#pragma unroll
        for (int i = 0; i < 4; ++i) {
            rowacc[i]     += fast_tanh(e0 + acc[ct][0][i]) * w30
                           + fast_tanh(e1 + acc[ct][1][i]) * w31;
            rowacc[4 + i] += fast_tanh(e0 + acc[ct][2][i]) * w30
                           + fast_tanh(e1 + acc[ct][3][i]) * w31;
        }
    }
    // reduce over the 16 lanes of each quad (cols)
#pragma unroll
    for (int off = 1; off < 16; off <<= 1)
#pragma unroll
        for (int i = 0; i < 8; ++i) rowacc[i] += __shfl_xor(rowacc[i], off, 16);

    // combine col-half partials via LDS (no atomics)
    const int rl = rbase_local + quad * 4;
    if (col_half == 1 && lcol == 0) {
#pragma unroll
        for (int i = 0; i < 4; ++i) {
            part[rl + i]      = rowacc[i];
            part[rl + 16 + i] = rowacc[4 + i];
        }
    }
    __syncthreads();
    if (col_half == 0 && lcol == 0) {
#pragma unroll
        for (int i = 0; i < 4; ++i) {
            logits[row0 + rl + i]      = rowacc[i]     + part[rl + i];
            logits[row0 + rl + 16 + i] = rowacc[4 + i] + part[rl + 16 + i];
        }
    }
}

// ---------------------------------------------------------------------------
// k3: per-batch softmax over L=8192 + inclusive cumsum -> sw (s), cw (c).
//     1024 threads/block (8 elems/thread).
// ---------------------------------------------------------------------------
__global__ __launch_bounds__(1024) void k3_softmax(const float* __restrict__ logits,
                                                   float* __restrict__ sw,
                                                   float* __restrict__ cw) {
    int b = blockIdx.x, t = threadIdx.x;
    const float* lg = logits + b * 8192;
    float v[8];
    float m = -1e30f;
#pragma unroll
    for (int i = 0; i < 8; ++i) { v[i] = lg[t * 8 + i]; m = fmaxf(m, v[i]); }
    __shared__ float red[1024];
    red[t] = m; __syncthreads();
    for (int s = 512; s > 0; s >>= 1) {
        if (t < s) red[t] = fmaxf(red[t], red[t + s]);
        __syncthreads();
    }
    float M = red[0]; __syncthreads();
    float sum = 0.f;
#pragma unroll
    for (int i = 0; i < 8; ++i) {
        v[i] = __builtin_amdgcn_exp2f((v[i] - M) * 1.4426950408889634f);
        sum += v[i];
    }
    red[t] = sum; __syncthreads();
    // Hillis-Steele inclusive scan over per-thread sums
    for (int off = 1; off < 1024; off <<= 1) {
        float add = (t >= off) ? red[t - off] : 0.f;
        __syncthreads();
        red[t] += add;
        __syncthreads();
    }
    float total = red[1023];
    float excl = red[t] - sum;              // exclusive prefix of thread sums
    float inv = 1.f / total;
    float run = excl;
#pragma unroll
    for (int i = 0; i < 8; ++i) {
        run += v[i];
        sw[b * 8192 + t * 8 + i] = v[i] * inv;
        cw[b * 8192 + t * 8 + i] = run * inv;
    }
}

// ---------------------------------------------------------------------------
// k4: out = (c-s)*pre + s*self + (1-c)*pos   (fp32 streaming, float4/thread,
//     grid-stride @2048 blocks). sents loaded normally (L3-warm from k2);
//     pre/pos/out use non-temporal hints to avoid evicting it.
// ---------------------------------------------------------------------------
__global__ __launch_bounds__(256) void k4_combine(const float* __restrict__ sents,
                                                  const float* __restrict__ pre,
                                                  const float* __restrict__ pos,
                                                  const float* __restrict__ sw,
                                                  const float* __restrict__ cw,
                                                  float* __restrict__ out) {
    const size_t stride = (size_t)gridDim.x * 256;
    for (size_t g = (size_t)blockIdx.x * 256 + threadIdx.x; g < 8388608ull; g += stride) {
        size_t base = g << 2;                           // 4 floats per thread
        int row = (int)(g >> 7);                        // 128 threads per row
        float s = sw[row], c = cw[row];
        float pw = c - s, qw = 1.0f - c;
        v4f a = *(const v4f*)&sents[base];
        v4f p = __builtin_nontemporal_load((const v4f*)&pre[base]);
        v4f q = __builtin_nontemporal_load((const v4f*)&pos[base]);
        v4f o = pw * p + s * a + qw * q;
        __builtin_nontemporal_store(o, (v4f*)&out[base]);
    }
}

// ---------------------------------------------------------------------------
extern "C" void kernel_launch(void* const* d_in, const int* in_sizes, int n_in,
                              void* d_out, int out_size, void* d_ws, size_t ws_size,
                              hipStream_t stream) {
    const float* emo   = (const float*)d_in[0];   // (8,1,512)
    const float* sents = (const float*)d_in[1];   // (8,8192,512)
    const float* pre   = (const float*)d_in[2];
    const float* pos   = (const float*)d_in[3];
    const float* W1    = (const float*)d_in[4];   // (512,512)
    const float* b1    = (const float*)d_in[5];
    const float* W2    = (const float*)d_in[6];   // (512,512)
    const float* b2    = (const float*)d_in[7];
    const float* W3    = (const float*)d_in[8];   // (512,1)
    // b3 = d_in[9]: constant shift -> cancels in softmax (and is zero)
    float* out = (float*)d_out;

    char* ws = (char*)d_ws;
    __bf16* w2f   = (__bf16*)ws;                    // 524288 B
    float* eqc    = (float*)(ws + 524288);          //  16384 B (8x512)
    float* logits = (float*)(ws + 540672);          // 262144 B (8x8192)
    float* sw     = (float*)(ws + 802816);          // 262144 B
    float* cw     = (float*)(ws + 1064960);         // 262144 B  (total ~1.27 MB)

    k01_prep<<<192, 256, 0, stream>>>(W2, w2f, emo, W1, b1, b2, eqc);
    k2_logits<<<1024, 256, 0, stream>>>(sents, w2f, eqc, W3, logits);
    k3_softmax<<<8, 1024, 0, stream>>>(logits, sw, cw);
    k4_combine<<<2048, 256, 0, stream>>>(sents, pre, pos, sw, cw, out);
}

// Round 3
// 439.655 us; speedup vs baseline: 1.2069x; 1.0857x over previous
//
#include <hip/hip_runtime.h>
#include <hip/hip_bf16.h>

typedef __bf16 v8bf __attribute__((ext_vector_type(8)));
typedef float  v4f  __attribute__((ext_vector_type(4)));

// fast tanh: (e^2x - 1) / (e^2x + 1) via v_exp_f32 + v_rcp_f32.
__device__ __forceinline__ float fast_tanh(float x) {
    x = fminf(fmaxf(x, -15.f), 15.f);
    float t = __builtin_amdgcn_exp2f(x * 2.885390081777927f);  // e^{2x}
    return (t - 1.f) * __builtin_amdgcn_rcpf(t + 1.f);
}

__device__ __forceinline__ v8bf cvt8(float4 f0, float4 f1) {
    v8bf v;
    v[0] = (__bf16)f0.x; v[1] = (__bf16)f0.y; v[2] = (__bf16)f0.z; v[3] = (__bf16)f0.w;
    v[4] = (__bf16)f1.x; v[5] = (__bf16)f1.y; v[6] = (__bf16)f1.z; v[7] = (__bf16)f1.w;
    return v;
}

// async global->LDS, 16B per lane, dest = uniform base + lane*16
__device__ __forceinline__ void gload16(const void* g, void* l) {
    __builtin_amdgcn_global_load_lds((const __attribute__((address_space(1))) unsigned int*)g,
                                     (__attribute__((address_space(3))) unsigned int*)l,
                                     16, 0, 0);
}

// ---------------------------------------------------------------------------
// k01: fused prep.
//  blocks 0..127  : W2 fp32 -> bf16 swizzle into MFMA B-fragment order
//                   w2f[ctg(32)][kt(16)][lane(64)][j(8)]; n=ctg*16+(lane&15),
//                   k=kt*32+(lane>>4)*8+j.
//  blocks 128..191: eqc[b][d] = (emotion[b,:] @ W1)[d] + b1[d] + b2[d]
// ---------------------------------------------------------------------------
__global__ __launch_bounds__(256) void k01_prep(const float* __restrict__ W2,
                                                __bf16* __restrict__ w2f,
                                                const float* __restrict__ emo,
                                                const float* __restrict__ W1,
                                                const float* __restrict__ b1,
                                                const float* __restrict__ b2,
                                                float* __restrict__ eqc) {
    if (blockIdx.x < 128) {
        int tid = blockIdx.x * 256 + threadIdx.x;   // 0..32767
        int ctg  = tid >> 10;                       // 0..31
        int kt   = (tid >> 6) & 15;                 // 0..15
        int lane = tid & 63;
        int quad = lane >> 4, col = lane & 15;
        int n = ctg * 16 + col;
        int kbase = kt * 32 + quad * 8;
        v8bf v;
#pragma unroll
        for (int j = 0; j < 8; ++j) v[j] = (__bf16)W2[(kbase + j) * 512 + n];
        *(v8bf*)&w2f[(size_t)tid * 8] = v;
    } else {
        __shared__ float part[4][64];
        int bb = blockIdx.x - 128;                  // 0..63
        int b = bb >> 3, d0 = (bb & 7) << 6;
        int t = threadIdx.x;
        int dl = t & 63, ks = t >> 6;               // wave-uniform ks
        const float* eb = emo + b * 512;
        float acc = 0.f;
        int kend = ks * 128 + 128;
        for (int k = ks * 128; k < kend; ++k)
            acc += eb[k] * W1[k * 512 + d0 + dl];
        part[ks][dl] = acc;
        __syncthreads();
        if (ks == 0) {
            int d = d0 + dl;
            float r = part[0][dl] + part[1][dl] + part[2][dl] + part[3][dl];
            eqc[b * 512 + d] = r + b1[d] + b2[d];
        }
    }
}

// ---------------------------------------------------------------------------
// k2: fused  logits[r] = sum_d tanh(eqc[b,d] + (sents@W2)[r,d]) * W3[d]
//     v3: T3-minimum 2-phase double-buffered LDS pipeline via global_load_lds
//     (round-2 post-mortem: reg-bound 2 waves/SIMD cannot hide the per-kt
//     chain of 20 dependent VMEM loads -> MfmaUtil 12%, 85% stall. DMA
//     staging needs no VGPRs; stage kt+1 flies under compute of kt, one
//     vmcnt(0)+barrier per K-step).
//     Per kt step: A chunk 64 rows x 32 k fp32 (8 KB), B slab 32k x 512n
//     bf16 frag-ordered (32 KB). LDS 2*(8+32) = 80 KB -> 2 blocks/CU.
//     A LDS layout [r(64)][slot(8)][16B] with slot = chunk ^ (r&7): XOR
//     pre-swizzle applied on the GLOBAL source (gload_lds writes linearly,
//     rule #21) -> ds_read_b128 at 128B row stride is ~2-way (free).
//     B chunks lane-linear (canonical conflict-free). B staged once/block
//     (halves L2 traffic vs per-col_half loads).
//     4 waves: (row_half, col_half) 2x2; each wave 32 rows x 256 cols,
//     acc[8][4]=128 regs; kt-outer, one A-frag pair feeds 8 col strips.
//     Layouts (learn_hip m89/m120): A: m=lane&15, k=quad*8+j;
//     B: n=lane&15, k=quad*8+j; C/D: col=lane&15, row=quad*4+reg.
// ---------------------------------------------------------------------------
__global__ __launch_bounds__(256, 2) void k2_logits(const float* __restrict__ sents,
                                                    const __bf16* __restrict__ w2f,
                                                    const float* __restrict__ eqc,
                                                    const float* __restrict__ W3,
                                                    float* __restrict__ logits) {
    __shared__ char smem[81920];   // [0,16K): A dbuf 2x8K ; [16K,80K): B dbuf 2x32K
    const int t = threadIdx.x;
    const int row0 = blockIdx.x * 64;           // global row base (b*L + l)
    const int bidx = row0 >> 13;                // batch index

    const int wave = t >> 6, lane = t & 63;
    const int quad = lane >> 4, lcol = lane & 15;
    const int row_half = wave >> 1, col_half = wave & 1;
    const int rbase_local = row_half * 32;

    // --- staging source pointers (per lane) ---
    // A: 2 insts/wave; inst i covers rows wave*16 + i*8 + (lane>>3), slot lane&7.
    //    LDS[r][s] receives global chunk s^(r&7)  (source pre-swizzle).
    const int rA0 = wave * 16 + (lane >> 3);
    const int rA1 = rA0 + 8;
    const int sA  = lane & 7;
    const char* pA0 = (const char*)sents + (size_t)(row0 + rA0) * 2048 + ((sA ^ (rA0 & 7)) << 4);
    const char* pA1 = (const char*)sents + (size_t)(row0 + rA1) * 2048 + ((sA ^ (rA1 & 7)) << 4);
    // B: 8 insts/wave; ctg = wave*8+i; src byte = ctg*16384 + kt*1024 + lane*16
    const char* pB = (const char*)w2f + (size_t)wave * 131072 + (lane << 4);
    char* lA = smem;            // + bb*8192  + (wave*2+i)*1024
    char* lB = smem + 16384;    // + bb*32768 + (wave*8+i)*1024

    // --- compute-side LDS addresses ---
    const int r0 = rbase_local + lcol;          // a0 row; a1 = r0+16 (same &7)
    const int swz = r0 & 7;
    const int a0c0 = ((2 * quad) ^ swz) << 4;       // chunk 2q   -> slot byte
    const int a0c1 = ((2 * quad + 1) ^ swz) << 4;   // chunk 2q+1 -> slot byte

    v4f acc[8][4];                              // [ct][{00,01,10,11}]
#pragma unroll
    for (int ct = 0; ct < 8; ++ct)
#pragma unroll
        for (int q = 0; q < 4; ++q) acc[ct][q] = (v4f){0.f, 0.f, 0.f, 0.f};

    // prologue: stage kt=0 into buf 0
    {
        gload16(pA0, lA + wave * 2048);
        gload16(pA1, lA + wave * 2048 + 1024);
#pragma unroll
        for (int i = 0; i < 8; ++i)
            gload16(pB + i * 16384, lB + (wave * 8 + i) * 1024);
    }
    __syncthreads();

    int cur = 0;
    for (int kt = 0; kt < 16; ++kt) {
        // phase 1: issue stage of kt+1 into the other buffer (in flight under compute)
        if (kt < 15) {
            const int nb = cur ^ 1;
            gload16(pA0 + (kt + 1) * 128, lA + nb * 8192 + wave * 2048);
            gload16(pA1 + (kt + 1) * 128, lA + nb * 8192 + wave * 2048 + 1024);
#pragma unroll
            for (int i = 0; i < 8; ++i)
                gload16(pB + i * 16384 + (kt + 1) * 1024, lB + nb * 32768 + (wave * 8 + i) * 1024);
        }
        // phase 2: compute current buffer
        const char* aRow0 = lA + cur * 8192 + r0 * 128;
        const char* bBase = lB + cur * 32768 + (lane << 4);
        float4 f00 = *(const float4*)(aRow0 + a0c0);
        float4 f01 = *(const float4*)(aRow0 + a0c1);
        float4 f10 = *(const float4*)(aRow0 + 16 * 128 + a0c0);
        float4 f11 = *(const float4*)(aRow0 + 16 * 128 + a0c1);
        v8bf a0 = cvt8(f00, f01);
        v8bf a1 = cvt8(f10, f11);
#pragma unroll
        for (int ct = 0; ct < 8; ++ct) {
            const int ctg = (col_half * 8 + ct) * 2;
            v8bf b0 = *(const v8bf*)(bBase + ctg * 1024);
            v8bf b1 = *(const v8bf*)(bBase + (ctg + 1) * 1024);
            acc[ct][0] = __builtin_amdgcn_mfma_f32_16x16x32_bf16(a0, b0, acc[ct][0], 0, 0, 0);
            acc[ct][1] = __builtin_amdgcn_mfma_f32_16x16x32_bf16(a0, b1, acc[ct][1], 0, 0, 0);
            acc[ct][2] = __builtin_amdgcn_mfma_f32_16x16x32_bf16(a1, b0, acc[ct][2], 0, 0, 0);
            acc[ct][3] = __builtin_amdgcn_mfma_f32_16x16x32_bf16(a1, b1, acc[ct][3], 0, 0, 0);
        }
        // phase 3: one drain+barrier per K-step (T3 minimum 2-phase)
        __syncthreads();
        cur ^= 1;
    }

    // epilogue: tanh(eqc + v) * W3, accumulate per-row partials in regs
    float rowacc[8] = {0.f, 0.f, 0.f, 0.f, 0.f, 0.f, 0.f, 0.f};
#pragma unroll
    for (int ct = 0; ct < 8; ++ct) {
        const int c0 = (col_half * 8 + ct) * 32;
        float e0  = eqc[bidx * 512 + c0 + lcol];
        float e1  = eqc[bidx * 512 + c0 + 16 + lcol];
        float w30 = W3[c0 + lcol];
        float w31 = W3[c0 + 16 + lcol];
#pragma unroll
        for (int i = 0; i < 4; ++i) {
            rowacc[i]     += fast_tanh(e0 + acc[ct][0][i]) * w30
                           + fast_tanh(e1 + acc[ct][1][i]) * w31;
            rowacc[4 + i] += fast_tanh(e0 + acc[ct][2][i]) * w30
                           + fast_tanh(e1 + acc[ct][3][i]) * w31;
        }
    }
    // reduce over the 16 lanes of each quad (cols)
#pragma unroll
    for (int off = 1; off < 16; off <<= 1)
#pragma unroll
        for (int i = 0; i < 8; ++i) rowacc[i] += __shfl_xor(rowacc[i], off, 16);

    // combine col-half partials via LDS (reuse smem; all k-loop reads done)
    float* part = (float*)smem;
    const int rl = rbase_local + quad * 4;
    if (col_half == 1 && lcol == 0) {
#pragma unroll
        for (int i = 0; i < 4; ++i) {
            part[rl + i]      = rowacc[i];
            part[rl + 16 + i] = rowacc[4 + i];
        }
    }
    __syncthreads();
    if (col_half == 0 && lcol == 0) {
#pragma unroll
        for (int i = 0; i < 4; ++i) {
            logits[row0 + rl + i]      = rowacc[i]     + part[rl + i];
            logits[row0 + rl + 16 + i] = rowacc[4 + i] + part[rl + 16 + i];
        }
    }
}

// ---------------------------------------------------------------------------
// k3: per-batch softmax over L=8192 + inclusive cumsum -> sw (s), cw (c).
// ---------------------------------------------------------------------------
__global__ __launch_bounds__(1024) void k3_softmax(const float* __restrict__ logits,
                                                   float* __restrict__ sw,
                                                   float* __restrict__ cw) {
    int b = blockIdx.x, t = threadIdx.x;
    const float* lg = logits + b * 8192;
    float v[8];
    float m = -1e30f;
#pragma unroll
    for (int i = 0; i < 8; ++i) { v[i] = lg[t * 8 + i]; m = fmaxf(m, v[i]); }
    __shared__ float red[1024];
    red[t] = m; __syncthreads();
    for (int s = 512; s > 0; s >>= 1) {
        if (t < s) red[t] = fmaxf(red[t], red[t + s]);
        __syncthreads();
    }
    float M = red[0]; __syncthreads();
    float sum = 0.f;
#pragma unroll
    for (int i = 0; i < 8; ++i) {
        v[i] = __builtin_amdgcn_exp2f((v[i] - M) * 1.4426950408889634f);
        sum += v[i];
    }
    red[t] = sum; __syncthreads();
    for (int off = 1; off < 1024; off <<= 1) {
        float add = (t >= off) ? red[t - off] : 0.f;
        __syncthreads();
        red[t] += add;
        __syncthreads();
    }
    float total = red[1023];
    float excl = red[t] - sum;
    float inv = 1.f / total;
    float run = excl;
#pragma unroll
    for (int i = 0; i < 8; ++i) {
        run += v[i];
        sw[b * 8192 + t * 8 + i] = v[i] * inv;
        cw[b * 8192 + t * 8 + i] = run * inv;
    }
}

// ---------------------------------------------------------------------------
// k4: out = (c-s)*pre + s*self + (1-c)*pos   (fp32 streaming, float4/thread,
//     grid-stride @2048 blocks).
// ---------------------------------------------------------------------------
__global__ __launch_bounds__(256) void k4_combine(const float* __restrict__ sents,
                                                  const float* __restrict__ pre,
                                                  const float* __restrict__ pos,
                                                  const float* __restrict__ sw,
                                                  const float* __restrict__ cw,
                                                  float* __restrict__ out) {
    const size_t stride = (size_t)gridDim.x * 256;
    for (size_t g = (size_t)blockIdx.x * 256 + threadIdx.x; g < 8388608ull; g += stride) {
        size_t base = g << 2;
        int row = (int)(g >> 7);
        float s = sw[row], c = cw[row];
        float pw = c - s, qw = 1.0f - c;
        v4f a = *(const v4f*)&sents[base];
        v4f p = __builtin_nontemporal_load((const v4f*)&pre[base]);
        v4f q = __builtin_nontemporal_load((const v4f*)&pos[base]);
        v4f o = pw * p + s * a + qw * q;
        __builtin_nontemporal_store(o, (v4f*)&out[base]);
    }
}

// ---------------------------------------------------------------------------
extern "C" void kernel_launch(void* const* d_in, const int* in_sizes, int n_in,
                              void* d_out, int out_size, void* d_ws, size_t ws_size,
                              hipStream_t stream) {
    const float* emo   = (const float*)d_in[0];   // (8,1,512)
    const float* sents = (const float*)d_in[1];   // (8,8192,512)
    const float* pre   = (const float*)d_in[2];
    const float* pos   = (const float*)d_in[3];
    const float* W1    = (const float*)d_in[4];   // (512,512)
    const float* b1    = (const float*)d_in[5];
    const float* W2    = (const float*)d_in[6];   // (512,512)
    const float* b2    = (const float*)d_in[7];
    const float* W3    = (const float*)d_in[8];   // (512,1)
    // b3 = d_in[9]: constant shift -> cancels in softmax (and is zero)
    float* out = (float*)d_out;

    char* ws = (char*)d_ws;
    __bf16* w2f   = (__bf16*)ws;                    // 524288 B
    float* eqc    = (float*)(ws + 524288);          //  16384 B (8x512)
    float* logits = (float*)(ws + 540672);          // 262144 B (8x8192)
    float* sw     = (float*)(ws + 802816);          // 262144 B
    float* cw     = (float*)(ws + 1064960);         // 262144 B

    k01_prep<<<192, 256, 0, stream>>>(W2, w2f, emo, W1, b1, b2, eqc);
    k2_logits<<<1024, 256, 0, stream>>>(sents, w2f, eqc, W3, logits);
    k3_softmax<<<8, 1024, 0, stream>>>(logits, sw, cw);
    k4_combine<<<2048, 256, 0, stream>>>(sents, pre, pos, sw, cw, out);
}